// Round 11
// baseline (111.453 us; speedup 1.0000x reference)
//
#include <hip/hip_runtime.h>
#include <hip/hip_fp16.h>
#include <hip/hip_cooperative_groups.h>

namespace cg = cooperative_groups;

#define BATCH  16384
#define NFEAT  50
#define DIM    128
#define NROWS  2000
#define TBL_HALFS (NROWS * DIM)            // 256000 halfs per table
#define WS_NEEDED (2u * TBL_HALFS * 2u)    // 1 MB
#define NCHUNKS (2 * NROWS * 16)           // 64000 8-half chunks

// ---------------------------------------------------------------------------
// Shared device body: convert one chunk of the f32 tables to f16 (permuted).
// Row layout: chunk c (16B = 8 halfs) holds dims {c*4..c*4+3, 64+c*4..67+c*4};
// quarter-lane q's 16B = dims {4q..4q+3, 64+4q..+3}, matching two contiguous
// f32 id-embedding dwordx4 reads at byte offsets 0 and 256.
__device__ __forceinline__ void convert_chunk(
    int u, const float* __restrict__ ufe, const float* __restrict__ ife,
    ushort* __restrict__ wsa)
{
    const int t   = (u >= NCHUNKS / 2) ? 1 : 0;
    const int rem = u - t * (NCHUNKS / 2);
    const int r = rem >> 4, c = rem & 15;
    const float* src = (t ? ife : ufe) + (size_t)r * DIM + c * 4;
    const float4 a = *reinterpret_cast<const float4*>(src);
    const float4 b = *reinterpret_cast<const float4*>(src + 64);
    __half2 hh[4];
    hh[0] = __floats2half2_rn(a.x, a.y);
    hh[1] = __floats2half2_rn(a.z, a.w);
    hh[2] = __floats2half2_rn(b.x, b.y);
    hh[3] = __floats2half2_rn(b.z, b.w);
    *reinterpret_cast<uint4*>(wsa + ((size_t)(t * NROWS + r) * 16 + c) * 8) =
        *reinterpret_cast<uint4*>(hh);
}

// Gather+dot for a 16-element tile (256 threads). meta = 2*16*NFEAT uints.
__device__ __forceinline__ void tile_body(
    int eb, uint* meta,
    const int* __restrict__ user_ids, const int* __restrict__ item_ids,
    const int* __restrict__ ufi, const float* __restrict__ ufv,
    const int* __restrict__ ifi, const float* __restrict__ ifv,
    const float* __restrict__ user_emb, const float* __restrict__ item_emb,
    const ushort* __restrict__ wsa, float* __restrict__ out)
{
    const int tid = threadIdx.x;

    #pragma unroll
    for (int rme = 0; rme < 4; ++rme) {
        const int k = rme * 256 + tid;
        if (k < 16 * NFEAT) {
            const uint  iu = (uint)ufi[(size_t)eb * NFEAT + k];
            const float vu = ufv[(size_t)eb * NFEAT + k];
            meta[k] = (iu & 0xffffu) |
                      ((uint)__half_as_ushort(__float2half_rn(vu)) << 16);
            const uint  ii = (uint)ifi[(size_t)eb * NFEAT + k];
            const float vi = ifv[(size_t)eb * NFEAT + k];
            meta[16 * NFEAT + k] = (ii & 0xffffu) |
                      ((uint)__half_as_ushort(__float2half_rn(vi)) << 16);
        }
    }
    __syncthreads();

    const int lane = tid & 63;
    const int w    = tid >> 6;
    const int q    = lane & 15;
    const int el   = w * 4 + (lane >> 4);
    const int e    = eb + el;

    const int uid = user_ids[e];
    const int iid = item_ids[e];
    const float4 ua = *reinterpret_cast<const float4*>(user_emb + (size_t)uid * DIM + q * 4);
    const float4 ub = *reinterpret_cast<const float4*>(user_emb + (size_t)uid * DIM + 64 + q * 4);
    const float4 va = *reinterpret_cast<const float4*>(item_emb + (size_t)iid * DIM + q * 4);
    const float4 vb = *reinterpret_cast<const float4*>(item_emb + (size_t)iid * DIM + 64 + q * 4);

    const uint* __restrict__ mu = meta + el * NFEAT;
    const uint* __restrict__ mi = meta + 16 * NFEAT + el * NFEAT;
    const ushort* __restrict__ tu_base = wsa;
    const ushort* __restrict__ ti_base = wsa + TBL_HALFS;

    __half2 au0 = __float2half2_rn(0.f), au1 = au0, au2 = au0, au3 = au0;
    __half2 ai0 = au0, ai1 = au0, ai2 = au0, ai3 = au0;

    #pragma unroll 10
    for (int f = 0; f < NFEAT; ++f) {
        const uint wu = mu[f];
        const uint wi = mi[f];
        const uint4 tu = *reinterpret_cast<const uint4*>(
            tu_base + (size_t)(wu & 0xffffu) * DIM + q * 8);
        const uint4 ti = *reinterpret_cast<const uint4*>(
            ti_base + (size_t)(wi & 0xffffu) * DIM + q * 8);
        const __half2 vu2 = __half2half2(__ushort_as_half((ushort)(wu >> 16)));
        const __half2 vi2 = __half2half2(__ushort_as_half((ushort)(wi >> 16)));
        const __half2* th = reinterpret_cast<const __half2*>(&tu);
        au0 = __hfma2(th[0], vu2, au0);
        au1 = __hfma2(th[1], vu2, au1);
        au2 = __hfma2(th[2], vu2, au2);
        au3 = __hfma2(th[3], vu2, au3);
        const __half2* ih = reinterpret_cast<const __half2*>(&ti);
        ai0 = __hfma2(ih[0], vi2, ai0);
        ai1 = __hfma2(ih[1], vi2, ai1);
        ai2 = __hfma2(ih[2], vi2, ai2);
        ai3 = __hfma2(ih[3], vi2, ai3);
    }

    const float2 du0 = __half22float2(au0), du1 = __half22float2(au1);
    const float2 du2 = __half22float2(au2), du3 = __half22float2(au3);
    const float2 dv0 = __half22float2(ai0), dv1 = __half22float2(ai1);
    const float2 dv2 = __half22float2(ai2), dv3 = __half22float2(ai3);

    float dot = (ua.x + du0.x) * (va.x + dv0.x)
              + (ua.y + du0.y) * (va.y + dv0.y)
              + (ua.z + du1.x) * (va.z + dv1.x)
              + (ua.w + du1.y) * (va.w + dv1.y)
              + (ub.x + du2.x) * (vb.x + dv2.x)
              + (ub.y + du2.y) * (vb.y + dv2.y)
              + (ub.z + du3.x) * (vb.z + dv3.x)
              + (ub.w + du3.y) * (vb.w + dv3.y);

    #pragma unroll
    for (int off = 8; off > 0; off >>= 1)
        dot += __shfl_xor(dot, off);

    if (q == 0) out[e] = dot;
}

// ---- Fused cooperative kernel (grid-stride: correct for ANY grid size) ------
__global__ __launch_bounds__(256) void mf_fused_gs(
    const float*  __restrict__ ufe,
    const float*  __restrict__ ife,
    const int*    __restrict__ user_ids,
    const int*    __restrict__ item_ids,
    const int*    __restrict__ ufi,
    const float*  __restrict__ ufv,
    const int*    __restrict__ ifi,
    const float*  __restrict__ ifv,
    const float*  __restrict__ user_emb,
    const float*  __restrict__ item_emb,
    ushort*       __restrict__ wsa,
    float*        __restrict__ out)
{
    __shared__ uint meta[2 * 16 * NFEAT];   // 6.4 KB
    const int tid    = threadIdx.x;
    const int stride = gridDim.x * 256;

    for (int u = blockIdx.x * 256 + tid; u < NCHUNKS; u += stride)
        convert_chunk(u, ufe, ife, wsa);

    __threadfence();            // ws visible across XCDs
    cg::this_grid().sync();

    for (int eb = blockIdx.x * 16; eb < BATCH; eb += gridDim.x * 16) {
        tile_body(eb, meta, user_ids, item_ids, ufi, ufv, ifi, ifv,
                  user_emb, item_emb, wsa, out);
        __syncthreads();        // meta reuse protection before next restage
    }
}

// ---- Two-kernel fallback path (R9, proven 27.9 us) --------------------------
__global__ __launch_bounds__(256) void k1_convert(
    const float* __restrict__ ufe,
    const float* __restrict__ ife,
    ushort*      __restrict__ wsa)
{
    const int u = blockIdx.x * 256 + threadIdx.x;
    if (u < NCHUNKS) convert_chunk(u, ufe, ife, wsa);
}

__global__ __launch_bounds__(256) void mf_dot_q(
    const int*    __restrict__ user_ids,
    const int*    __restrict__ item_ids,
    const int*    __restrict__ ufi,
    const float*  __restrict__ ufv,
    const int*    __restrict__ ifi,
    const float*  __restrict__ ifv,
    const float*  __restrict__ user_emb,
    const float*  __restrict__ item_emb,
    const ushort* __restrict__ wsa,
    float*        __restrict__ out)
{
    __shared__ uint meta[2 * 16 * NFEAT];
    tile_body(blockIdx.x * 16, meta, user_ids, item_ids, ufi, ufv, ifi, ifv,
              user_emb, item_emb, wsa, out);
}

// ---- Last-resort fallback: all-f32 single-pass (if ws too small) ------------
__global__ __launch_bounds__(256) void mf_dot_fallback(
    const int*   __restrict__ user_ids,
    const int*   __restrict__ item_ids,
    const int*   __restrict__ ufi,
    const float* __restrict__ ufv,
    const int*   __restrict__ ifi,
    const float* __restrict__ ifv,
    const float* __restrict__ user_emb,
    const float* __restrict__ item_emb,
    const float* __restrict__ user_feat_emb,
    const float* __restrict__ item_feat_emb,
    float*       __restrict__ out)
{
    const int tid  = threadIdx.x;
    const int lane = tid & 63;
    const int half = lane >> 5;
    const int sl   = lane & 31;
    const int d0   = sl * 4;

    int wv = (int)((blockIdx.x * blockDim.x + tid) >> 6);
    wv = __builtin_amdgcn_readfirstlane(wv);
    const int b0 = wv * 2, b1 = b0 + 1;
    const int b  = half ? b1 : b0;

    const int uid0 = user_ids[b0], uid1 = user_ids[b1];
    const int iid0 = item_ids[b0], iid1 = item_ids[b1];
    const int urow = half ? uid1 : uid0;
    const int irow = half ? iid1 : iid0;

    float4 uacc = *reinterpret_cast<const float4*>(user_emb + (size_t)urow * DIM + d0);
    float4 vacc = *reinterpret_cast<const float4*>(item_emb + (size_t)irow * DIM + d0);

    #pragma unroll 10
    for (int f = 0; f < NFEAT; ++f) {
        const int   ui0 = ufi[b0 * NFEAT + f], ui1 = ufi[b1 * NFEAT + f];
        const float uv0 = ufv[b0 * NFEAT + f], uv1 = ufv[b1 * NFEAT + f];
        const int   ii0 = ifi[b0 * NFEAT + f], ii1 = ifi[b1 * NFEAT + f];
        const float iv0 = ifv[b0 * NFEAT + f], iv1 = ifv[b1 * NFEAT + f];

        const int   ur = half ? ui1 : ui0;
        const float uw = half ? uv1 : uv0;
        const int   ir = half ? ii1 : ii0;
        const float iw = half ? iv1 : iv0;

        const float4 ue = *reinterpret_cast<const float4*>(user_feat_emb + (size_t)ur * DIM + d0);
        const float4 ie = *reinterpret_cast<const float4*>(item_feat_emb + (size_t)ir * DIM + d0);

        uacc.x = fmaf(uw, ue.x, uacc.x);
        uacc.y = fmaf(uw, ue.y, uacc.y);
        uacc.z = fmaf(uw, ue.z, uacc.z);
        uacc.w = fmaf(uw, ue.w, uacc.w);
        vacc.x = fmaf(iw, ie.x, vacc.x);
        vacc.y = fmaf(iw, ie.y, vacc.y);
        vacc.z = fmaf(iw, ie.z, vacc.z);
        vacc.w = fmaf(iw, ie.w, vacc.w);
    }

    float dot = uacc.x * vacc.x + uacc.y * vacc.y + uacc.z * vacc.z + uacc.w * vacc.w;
    #pragma unroll
    for (int off = 16; off > 0; off >>= 1)
        dot += __shfl_xor(dot, off);
    if (sl == 0) out[b] = dot;
}

extern "C" void kernel_launch(void* const* d_in, const int* in_sizes, int n_in,
                              void* d_out, int out_size, void* d_ws, size_t ws_size,
                              hipStream_t stream) {
    const float* ufe = (const float*)d_in[8];
    const float* ife = (const float*)d_in[9];
    const int* user_ids = (const int*)d_in[0];
    const int* item_ids = (const int*)d_in[1];
    const int* ufi = (const int*)d_in[2];
    const float* ufv = (const float*)d_in[3];
    const int* ifi = (const int*)d_in[4];
    const float* ifv = (const float*)d_in[5];
    const float* user_emb = (const float*)d_in[6];
    const float* item_emb = (const float*)d_in[7];
    float* out = (float*)d_out;

    if (ws_size < WS_NEEDED) {
        mf_dot_fallback<<<BATCH / 8, 256, 0, stream>>>(
            user_ids, item_ids, ufi, ufv, ifi, ifv,
            user_emb, item_emb, ufe, ife, out);
        return;
    }

    ushort* wsa = (ushort*)d_ws;

    // Size the cooperative grid from the runtime's own occupancy model
    // (host-side queries only; graph-capture safe).
    int grid = 0;
    {
        int occ = 0, ncu = 0, dev = 0;
        (void)hipGetDevice(&dev);
        (void)hipOccupancyMaxActiveBlocksPerMultiprocessor(
            &occ, (const void*)mf_fused_gs, 256, 0);
        (void)hipDeviceGetAttribute(&ncu, hipDeviceAttributeMultiprocessorCount, dev);
        if (occ > 0 && ncu > 0) {
            long cap = (long)occ * (long)ncu;
            grid = (int)(cap < (BATCH / 16) ? cap : (BATCH / 16));
        }
    }

    bool launched = false;
    if (grid > 0) {
        void* args[] = {
            (void*)&ufe, (void*)&ife,
            (void*)&user_ids, (void*)&item_ids,
            (void*)&ufi, (void*)&ufv, (void*)&ifi, (void*)&ifv,
            (void*)&user_emb, (void*)&item_emb,
            (void*)&wsa, (void*)&out,
        };
        hipError_t err = hipLaunchCooperativeKernel(
            (const void*)mf_fused_gs, dim3(grid), dim3(256), args, 0, stream);
        launched = (err == hipSuccess);
        if (!launched) (void)hipGetLastError();   // clear sticky error
    }

    if (!launched) {
        k1_convert<<<(NCHUNKS + 255) / 256, 256, 0, stream>>>(ufe, ife, wsa);
        mf_dot_q<<<BATCH / 16, 256, 0, stream>>>(
            user_ids, item_ids, ufi, ufv, ifi, ifv,
            user_emb, item_emb, wsa, out);
    }
}

// Round 12
// 27.620 us; speedup vs baseline: 4.0353x; 4.0353x over previous
//
#include <hip/hip_runtime.h>
#include <hip/hip_fp16.h>

#define BATCH  16384
#define NFEAT  50
#define DIM    128
#define NROWS  2000
#define TBL_HALFS (NROWS * DIM)            // 256000 halfs per table
#define WS_NEEDED (2u * TBL_HALFS * 2u)    // 1 MB
#define NCHUNKS (2 * NROWS * 16)           // 64000 8-half chunks

// ---- K1: convert f32 feature tables -> f16, with dim permutation -----------
// Row layout: chunk c (16B = 8 halfs) holds dims {c*4..c*4+3, 64+c*4..67+c*4};
// quarter-lane q's 16B = dims {4q..4q+3, 64+4q..+3}, matching two contiguous
// f32 id-embedding dwordx4 reads at byte offsets 0 and 256.
__global__ __launch_bounds__(512) void k1_convert(
    const float* __restrict__ ufe,
    const float* __restrict__ ife,
    ushort*      __restrict__ wsa)
{
    const int u = blockIdx.x * 512 + threadIdx.x;   // 125*512 = 64000 exactly
    const int t   = (u >= NCHUNKS / 2) ? 1 : 0;
    const int rem = u - t * (NCHUNKS / 2);
    const int r = rem >> 4, c = rem & 15;
    const float* src = (t ? ife : ufe) + (size_t)r * DIM + c * 4;
    const float4 a = *reinterpret_cast<const float4*>(src);
    const float4 b = *reinterpret_cast<const float4*>(src + 64);
    __half2 hh[4];
    hh[0] = __floats2half2_rn(a.x, a.y);
    hh[1] = __floats2half2_rn(a.z, a.w);
    hh[2] = __floats2half2_rn(b.x, b.y);
    hh[3] = __floats2half2_rn(b.z, b.w);
    *reinterpret_cast<uint4*>(wsa + ((size_t)(t * NROWS + r) * 16 + c) * 8) =
        *reinterpret_cast<uint4*>(hh);
}

// ---- Main: quarter-wave f16 gathers, 4 elements per wave (R9 structure) -----
__global__ __launch_bounds__(256) void mf_dot_q(
    const int*    __restrict__ user_ids,
    const int*    __restrict__ item_ids,
    const int*    __restrict__ ufi,
    const float*  __restrict__ ufv,
    const int*    __restrict__ ifi,
    const float*  __restrict__ ifv,
    const float*  __restrict__ user_emb,
    const float*  __restrict__ item_emb,
    const ushort* __restrict__ wsa,
    float*        __restrict__ out)
{
    __shared__ uint meta[2 * 16 * NFEAT];   // 6.4 KB

    const int tid = threadIdx.x;
    const int eb  = blockIdx.x * 16;        // 16 elements per block

    // ---- stage packed (idx | f16val) meta, paired dwordx2 loads ----
    #pragma unroll
    for (int rme = 0; rme < 2; ++rme) {
        const int k2 = rme * 512 + tid * 2;          // even, 0..1022
        if (k2 < 16 * NFEAT) {
            const int2   iu2 = *reinterpret_cast<const int2*>(ufi + (size_t)eb * NFEAT + k2);
            const float2 vu2 = *reinterpret_cast<const float2*>(ufv + (size_t)eb * NFEAT + k2);
            meta[k2]     = ((uint)iu2.x & 0xffffu) |
                           ((uint)__half_as_ushort(__float2half_rn(vu2.x)) << 16);
            meta[k2 + 1] = ((uint)iu2.y & 0xffffu) |
                           ((uint)__half_as_ushort(__float2half_rn(vu2.y)) << 16);
            const int2   ii2 = *reinterpret_cast<const int2*>(ifi + (size_t)eb * NFEAT + k2);
            const float2 vi2 = *reinterpret_cast<const float2*>(ifv + (size_t)eb * NFEAT + k2);
            meta[16 * NFEAT + k2]     = ((uint)ii2.x & 0xffffu) |
                           ((uint)__half_as_ushort(__float2half_rn(vi2.x)) << 16);
            meta[16 * NFEAT + k2 + 1] = ((uint)ii2.y & 0xffffu) |
                           ((uint)__half_as_ushort(__float2half_rn(vi2.y)) << 16);
        }
    }
    __syncthreads();

    const int lane = tid & 63;
    const int w    = tid >> 6;
    const int q    = lane & 15;             // lane within quarter
    const int el   = w * 4 + (lane >> 4);   // local element 0..15
    const int e    = eb + el;

    const int uid = user_ids[e];
    const int iid = item_ids[e];
    const float4 ua = *reinterpret_cast<const float4*>(user_emb + (size_t)uid * DIM + q * 4);
    const float4 ub = *reinterpret_cast<const float4*>(user_emb + (size_t)uid * DIM + 64 + q * 4);
    const float4 va = *reinterpret_cast<const float4*>(item_emb + (size_t)iid * DIM + q * 4);
    const float4 vb = *reinterpret_cast<const float4*>(item_emb + (size_t)iid * DIM + 64 + q * 4);

    const uint* __restrict__ mu = meta + el * NFEAT;
    const uint* __restrict__ mi = meta + 16 * NFEAT + el * NFEAT;
    const ushort* __restrict__ tu_base = wsa;
    const ushort* __restrict__ ti_base = wsa + TBL_HALFS;

    __half2 au0 = __float2half2_rn(0.f), au1 = au0, au2 = au0, au3 = au0;
    __half2 ai0 = au0, ai1 = au0, ai2 = au0, ai3 = au0;

    #pragma unroll 10
    for (int f = 0; f < NFEAT; ++f) {
        const uint wu = mu[f];
        const uint wi = mi[f];

        const uint4 tu = *reinterpret_cast<const uint4*>(
            tu_base + (size_t)(wu & 0xffffu) * DIM + q * 8);
        const uint4 ti = *reinterpret_cast<const uint4*>(
            ti_base + (size_t)(wi & 0xffffu) * DIM + q * 8);

        const __half2 vu2 = __half2half2(__ushort_as_half((ushort)(wu >> 16)));
        const __half2 vi2 = __half2half2(__ushort_as_half((ushort)(wi >> 16)));

        const __half2* th = reinterpret_cast<const __half2*>(&tu);
        au0 = __hfma2(th[0], vu2, au0);
        au1 = __hfma2(th[1], vu2, au1);
        au2 = __hfma2(th[2], vu2, au2);
        au3 = __hfma2(th[3], vu2, au3);
        const __half2* ih = reinterpret_cast<const __half2*>(&ti);
        ai0 = __hfma2(ih[0], vi2, ai0);
        ai1 = __hfma2(ih[1], vi2, ai1);
        ai2 = __hfma2(ih[2], vi2, ai2);
        ai3 = __hfma2(ih[3], vi2, ai3);
    }

    const float2 du0 = __half22float2(au0), du1 = __half22float2(au1);
    const float2 du2 = __half22float2(au2), du3 = __half22float2(au3);
    const float2 dv0 = __half22float2(ai0), dv1 = __half22float2(ai1);
    const float2 dv2 = __half22float2(ai2), dv3 = __half22float2(ai3);

    float dot = (ua.x + du0.x) * (va.x + dv0.x)
              + (ua.y + du0.y) * (va.y + dv0.y)
              + (ua.z + du1.x) * (va.z + dv1.x)
              + (ua.w + du1.y) * (va.w + dv1.y)
              + (ub.x + du2.x) * (vb.x + dv2.x)
              + (ub.y + du2.y) * (vb.y + dv2.y)
              + (ub.z + du3.x) * (vb.z + dv3.x)
              + (ub.w + du3.y) * (vb.w + dv3.y);

    #pragma unroll
    for (int off = 8; off > 0; off >>= 1)
        dot += __shfl_xor(dot, off);

    if (q == 0) out[e] = dot;
}

// ---- Fallback: all-f32 single-pass (if ws too small) ------------------------
__global__ __launch_bounds__(256) void mf_dot_fallback(
    const int*   __restrict__ user_ids,
    const int*   __restrict__ item_ids,
    const int*   __restrict__ ufi,
    const float* __restrict__ ufv,
    const int*   __restrict__ ifi,
    const float* __restrict__ ifv,
    const float* __restrict__ user_emb,
    const float* __restrict__ item_emb,
    const float* __restrict__ user_feat_emb,
    const float* __restrict__ item_feat_emb,
    float*       __restrict__ out)
{
    const int tid  = threadIdx.x;
    const int lane = tid & 63;
    const int half = lane >> 5;
    const int sl   = lane & 31;
    const int d0   = sl * 4;

    int wv = (int)((blockIdx.x * blockDim.x + tid) >> 6);
    wv = __builtin_amdgcn_readfirstlane(wv);
    const int b0 = wv * 2, b1 = b0 + 1;
    const int b  = half ? b1 : b0;

    const int uid0 = user_ids[b0], uid1 = user_ids[b1];
    const int iid0 = item_ids[b0], iid1 = item_ids[b1];
    const int urow = half ? uid1 : uid0;
    const int irow = half ? iid1 : iid0;

    float4 uacc = *reinterpret_cast<const float4*>(user_emb + (size_t)urow * DIM + d0);
    float4 vacc = *reinterpret_cast<const float4*>(item_emb + (size_t)irow * DIM + d0);

    #pragma unroll 10
    for (int f = 0; f < NFEAT; ++f) {
        const int   ui0 = ufi[b0 * NFEAT + f], ui1 = ufi[b1 * NFEAT + f];
        const float uv0 = ufv[b0 * NFEAT + f], uv1 = ufv[b1 * NFEAT + f];
        const int   ii0 = ifi[b0 * NFEAT + f], ii1 = ifi[b1 * NFEAT + f];
        const float iv0 = ifv[b0 * NFEAT + f], iv1 = ifv[b1 * NFEAT + f];

        const int   ur = half ? ui1 : ui0;
        const float uw = half ? uv1 : uv0;
        const int   ir = half ? ii1 : ii0;
        const float iw = half ? iv1 : iv0;

        const float4 ue = *reinterpret_cast<const float4*>(user_feat_emb + (size_t)ur * DIM + d0);
        const float4 ie = *reinterpret_cast<const float4*>(item_feat_emb + (size_t)ir * DIM + d0);

        uacc.x = fmaf(uw, ue.x, uacc.x);
        uacc.y = fmaf(uw, ue.y, uacc.y);
        uacc.z = fmaf(uw, ue.z, uacc.z);
        uacc.w = fmaf(uw, ue.w, uacc.w);
        vacc.x = fmaf(iw, ie.x, vacc.x);
        vacc.y = fmaf(iw, ie.y, vacc.y);
        vacc.z = fmaf(iw, ie.z, vacc.z);
        vacc.w = fmaf(iw, ie.w, vacc.w);
    }

    float dot = uacc.x * vacc.x + uacc.y * vacc.y + uacc.z * vacc.z + uacc.w * vacc.w;
    #pragma unroll
    for (int off = 16; off > 0; off >>= 1)
        dot += __shfl_xor(dot, off);
    if (sl == 0) out[b] = dot;
}

extern "C" void kernel_launch(void* const* d_in, const int* in_sizes, int n_in,
                              void* d_out, int out_size, void* d_ws, size_t ws_size,
                              hipStream_t stream) {
    const int*   user_ids      = (const int*)  d_in[0];
    const int*   item_ids      = (const int*)  d_in[1];
    const int*   ufi           = (const int*)  d_in[2];
    const float* ufv           = (const float*)d_in[3];
    const int*   ifi           = (const int*)  d_in[4];
    const float* ifv           = (const float*)d_in[5];
    const float* user_emb      = (const float*)d_in[6];
    const float* item_emb      = (const float*)d_in[7];
    const float* user_feat_emb = (const float*)d_in[8];
    const float* item_feat_emb = (const float*)d_in[9];
    float* out = (float*)d_out;

    if (ws_size >= WS_NEEDED) {
        ushort* wsa = (ushort*)d_ws;
        k1_convert<<<NCHUNKS / 512, 512, 0, stream>>>(user_feat_emb, item_feat_emb, wsa);
        mf_dot_q<<<BATCH / 16, 256, 0, stream>>>(
            user_ids, item_ids, ufi, ufv, ifi, ifv,
            user_emb, item_emb, wsa, out);
    } else {
        mf_dot_fallback<<<BATCH / 8, 256, 0, stream>>>(
            user_ids, item_ids, ufi, ufv, ifi, ifv,
            user_emb, item_emb, user_feat_emb, item_feat_emb, out);
    }
}